// Round 12
// baseline (279.865 us; speedup 1.0000x reference)
//
#include <hip/hip_runtime.h>
#include <hip/hip_fp16.h>
#include <math.h>

#define N_NODES 100000
#define N_EDGES 1600000
#define HID 32
#define BN_EPS 1e-3f
#define NBUCK 782        // buckets of 128 nodes
#define CAPB 2432        // slots per bucket (mean 2046, 8.5 sigma headroom)
#define BIN_E 4096       // edges per binning block
#define OVF_MAX 65536
#define NB32 3125        // node blocks: 32 nodes each, 3125*32 = 100000 exactly

__device__ __forceinline__ float eluf(float x) { return x > 0.f ? x : expm1f(x); }

// monotonic order-preserving encode float -> uint (0 = unreachable sentinel for finite inputs)
__device__ __forceinline__ unsigned int encf(float f) {
    unsigned int u = __float_as_uint(f);
    return (u & 0x80000000u) ? ~u : (u | 0x80000000u);
}
__device__ __forceinline__ float decf(unsigned int k) {
    return __uint_as_float((k & 0x80000000u) ? (k & 0x7FFFFFFFu) : ~k);
}

// ---------------- kernel 1: node encoder (8 lanes/node) + BN1 partial stats ------------
__global__ __launch_bounds__(256) void k_encode(
    const float* __restrict__ x_cont, const int* __restrict__ x_cat,
    const float* __restrict__ datanorm,
    const float* __restrict__ W_cont, const float* __restrict__ b_cont,
    const float* __restrict__ emb_charge, const float* __restrict__ emb_pdg,
    const float* __restrict__ W_cat, const float* __restrict__ b_cat,
    const float* __restrict__ W_enc, const float* __restrict__ b_enc,
    float* __restrict__ emb_out, float* __restrict__ sum1, float* __restrict__ sumsq1)
{
    __shared__ __align__(16) float sWc[6 * 16];
    __shared__ __align__(16) float sWcat[16 * 16];
    __shared__ __align__(16) float sWenc[32 * 32];
    __shared__ float sbc[16], sbcat[16], sbenc[32];
    __shared__ float sdn[6], sech[3 * 8], sepd[7 * 8];
    __shared__ float sIN[32][33];      // [node][in32 channel], pad 33
    __shared__ float ps[4][32], pq[4][32];

    int tid = threadIdx.x;
    for (int t = tid; t < 96; t += 256) sWc[t] = W_cont[t];
    sWcat[tid] = W_cat[tid];
    for (int t = tid; t < 1024; t += 256) sWenc[t] = W_enc[t];
    if (tid < 16) { sbc[tid] = b_cont[tid]; sbcat[tid] = b_cat[tid]; }
    if (tid < 32) sbenc[tid] = b_enc[tid];
    if (tid < 6)  sdn[tid] = datanorm[tid];
    if (tid < 24) sech[tid] = emb_charge[tid];
    if (tid < 56) sepd[tid] = emb_pdg[tid];
    __syncthreads();

    int grp = tid >> 3;                 // node slot 0..31
    int sub = tid & 7;
    int n = blockIdx.x * 32 + grp;      // grid NB32 -> always < N_NODES

    float xc[6];
#pragma unroll
    for (int i = 0; i < 6; i++) xc[i] = x_cont[n * 6 + i] * sdn[i];
    int pdg = x_cat[n * 2 + 0], chg = x_cat[n * 2 + 1];
    int p = pdg < 0 ? -pdg : pdg;
    int pidx;
    switch (p) {
        case 1: pidx = 0; break; case 2: pidx = 1; break;
        case 11: pidx = 2; break; case 13: pidx = 3; break;
        case 22: pidx = 4; break; case 130: pidx = 5; break;
        case 211: pidx = 6; break; default: pidx = 0; break;
    }

    // stage 1: emb_cont cols c0, c0+1  (c0 = sub*2)
    int c0 = sub * 2;
    float a0 = sbc[c0], a1 = sbc[c0 + 1];
#pragma unroll
    for (int i = 0; i < 6; i++) {
        a0 += xc[i] * sWc[i * 16 + c0];
        a1 += xc[i] * sWc[i * 16 + c0 + 1];
    }
    float cont0 = eluf(a0), cont1 = eluf(a1);

    // stage 2: emb_cat cols c0, c0+1 over cin[16] = [charge(8), pdg(8)]
    float cin[16];
#pragma unroll
    for (int k = 0; k < 8; k++) cin[k] = sech[(chg + 1) * 8 + k];
#pragma unroll
    for (int k = 0; k < 8; k++) cin[8 + k] = sepd[pidx * 8 + k];
    float b0 = sbcat[c0], b1 = sbcat[c0 + 1];
#pragma unroll
    for (int i = 0; i < 16; i++) {
        b0 += cin[i] * sWcat[i * 16 + c0];
        b1 += cin[i] * sWcat[i * 16 + c0 + 1];
    }
    float cat0 = eluf(b0), cat1 = eluf(b1);

    // exchange: in32 = [cat(0..15), cont(16..31)]
    sIN[grp][c0 + 0] = cat0;  sIN[grp][c0 + 1] = cat1;
    sIN[grp][16 + c0 + 0] = cont0; sIN[grp][16 + c0 + 1] = cont1;
    __syncthreads();   // explicit barrier: wave-sync LDS exchange proved replay-unstable (R11)

    // stage 3: e cols sub*4 .. sub*4+3
    int c4 = sub * 4;
    float e0 = sbenc[c4], e1 = sbenc[c4 + 1], e2 = sbenc[c4 + 2], e3 = sbenc[c4 + 3];
#pragma unroll
    for (int i = 0; i < 32; i++) {
        float x = sIN[grp][i];
        const float4 w = *(const float4*)&sWenc[i * 32 + c4];
        e0 += x * w.x; e1 += x * w.y; e2 += x * w.z; e3 += x * w.w;
    }
    e0 = eluf(e0); e1 = eluf(e1); e2 = eluf(e2); e3 = eluf(e3);
    *(float4*)(emb_out + (size_t)n * 32 + c4) = make_float4(e0, e1, e2, e3);

    // BN1 partial stats: reduce over the 8 node-groups in this wave
    float s0 = e0, s1 = e1, s2 = e2, s3 = e3;
    float q0 = e0 * e0, q1 = e1 * e1, q2 = e2 * e2, q3 = e3 * e3;
#pragma unroll
    for (int o = 8; o < 64; o <<= 1) {
        s0 += __shfl_xor(s0, o, 64); s1 += __shfl_xor(s1, o, 64);
        s2 += __shfl_xor(s2, o, 64); s3 += __shfl_xor(s3, o, 64);
        q0 += __shfl_xor(q0, o, 64); q1 += __shfl_xor(q1, o, 64);
        q2 += __shfl_xor(q2, o, 64); q3 += __shfl_xor(q3, o, 64);
    }
    int lane = tid & 63, wid = tid >> 6;
    if (lane < 8) {
        ps[wid][lane * 4 + 0] = s0; ps[wid][lane * 4 + 1] = s1;
        ps[wid][lane * 4 + 2] = s2; ps[wid][lane * 4 + 3] = s3;
        pq[wid][lane * 4 + 0] = q0; pq[wid][lane * 4 + 1] = q1;
        pq[wid][lane * 4 + 2] = q2; pq[wid][lane * 4 + 3] = q3;
    }
    __syncthreads();
    if (tid < 32) {
        atomicAdd(&sum1[tid], ps[0][tid] + ps[1][tid] + ps[2][tid] + ps[3][tid]);
        atomicAdd(&sumsq1[tid], pq[0][tid] + pq[1][tid] + pq[2][tid] + pq[3][tid]);
    }
}

// ---------------- kernel 2: BN1 affine -> A [fp32], B [fp16] (8 lanes/node) ------------
__global__ __launch_bounds__(256) void k_normAB(
    const float* __restrict__ emb,     // raw (pre-BN); NOT modified
    const float* __restrict__ W_msg,
    const float* __restrict__ g, const float* __restrict__ be,
    const float* __restrict__ sum1, const float* __restrict__ sumsq1,
    float* __restrict__ A, __half* __restrict__ Bh)
{
    __shared__ __align__(16) float sWA[32 * 32];
    __shared__ __align__(16) float sWB[32 * 32];
    __shared__ float sa1[32], sb1[32];
    __shared__ float sE[32][33];
    int tid = threadIdx.x;
    for (int t = tid; t < 1024; t += 256) {
        float w0 = W_msg[t];
        float w1 = W_msg[1024 + t];
        sWA[t] = w0 - w1;
        sWB[t] = w1;
    }
    if (tid < 32) {
        float m = sum1[tid] / (float)N_NODES;
        float v = sumsq1[tid] / (float)N_NODES - m * m;
        float i1 = 1.0f / sqrtf(v + BN_EPS);
        float a1 = g[tid] * i1;
        sa1[tid] = a1;
        sb1[tid] = be[tid] - a1 * m;
    }
    __syncthreads();

    int grp = tid >> 3, sub = tid & 7;
    int n = blockIdx.x * 32 + grp;
    int c4 = sub * 4;

    float4 ev = *(const float4*)(emb + (size_t)n * 32 + c4);
    sE[grp][c4 + 0] = sa1[c4 + 0] * ev.x + sb1[c4 + 0];
    sE[grp][c4 + 1] = sa1[c4 + 1] * ev.y + sb1[c4 + 1];
    sE[grp][c4 + 2] = sa1[c4 + 2] * ev.z + sb1[c4 + 2];
    sE[grp][c4 + 3] = sa1[c4 + 3] * ev.w + sb1[c4 + 3];
    __syncthreads();   // explicit barrier (R11 lesson)

    float a0 = 0.f, a1 = 0.f, a2 = 0.f, a3 = 0.f;
    float b0 = 0.f, b1 = 0.f, b2 = 0.f, b3 = 0.f;
#pragma unroll
    for (int i = 0; i < 32; i++) {
        float x = sE[grp][i];
        const float4 wa = *(const float4*)&sWA[i * 32 + c4];
        const float4 wb = *(const float4*)&sWB[i * 32 + c4];
        a0 += x * wa.x; a1 += x * wa.y; a2 += x * wa.z; a3 += x * wa.w;
        b0 += x * wb.x; b1 += x * wb.y; b2 += x * wb.z; b3 += x * wb.w;
    }
    *(float4*)(A + (size_t)n * 32 + c4) = make_float4(a0, a1, a2, a3);

    unsigned int lo = ((unsigned int)__half_as_ushort(__float2half_rn(b1)) << 16)
                    | (unsigned int)__half_as_ushort(__float2half_rn(b0));
    unsigned int hi = ((unsigned int)__half_as_ushort(__float2half_rn(b3)) << 16)
                    | (unsigned int)__half_as_ushort(__float2half_rn(b2));
    *(uint2*)(Bh + (size_t)n * 32 + c4) = make_uint2(lo, hi);
}

// ---------------- kernel 3: LDS-staged multisplit binning of edges by dst bucket -------
// Packed entry: (dst & 127) << 17 | src   (src < 131072)
__global__ __launch_bounds__(1024) void k_bin(
    const int* __restrict__ src, const int* __restrict__ dst,
    int* __restrict__ cnt, unsigned int* __restrict__ eidx,
    unsigned long long* __restrict__ ovf, int* __restrict__ ovfn)
{
    __shared__ unsigned int lcnt[NBUCK];
    __shared__ unsigned int lbase[NBUCK];
    __shared__ unsigned int gbase[NBUCK];
    __shared__ unsigned int sc[1024];
    __shared__ unsigned int sg[BIN_E];
    __shared__ unsigned int sd[BIN_E];
    __shared__ unsigned int s_total;

    int tid = threadIdx.x;
    for (int i = tid; i < NBUCK; i += 1024) lcnt[i] = 0;
    __syncthreads();

    int e0 = blockIdx.x * BIN_E;
    int b_[4]; unsigned int p_[4], r_[4]; bool v_[4];
#pragma unroll
    for (int i = 0; i < 4; i++) {
        int e = e0 + i * 1024 + tid;
        v_[i] = (e < N_EDGES);
        b_[i] = 0; p_[i] = 0; r_[i] = 0;
        if (v_[i]) {
            int d = dst[e], s = src[e];
            b_[i] = d >> 7;
            p_[i] = ((unsigned int)(d & 127) << 17) | (unsigned int)s;
            r_[i] = atomicAdd(&lcnt[b_[i]], 1u);
        }
    }
    __syncthreads();

    // exclusive scan of lcnt over NBUCK (Hillis-Steele, 1024 wide)
    sc[tid] = (tid < NBUCK) ? lcnt[tid] : 0;
    __syncthreads();
    for (int o = 1; o < 1024; o <<= 1) {
        unsigned int u = (tid >= o) ? sc[tid - o] : 0;
        __syncthreads();
        sc[tid] += u;
        __syncthreads();
    }
    if (tid < NBUCK) lbase[tid] = sc[tid] - lcnt[tid];
    if (tid == 0) s_total = sc[1023];
    if (tid < NBUCK && lcnt[tid] > 0)
        gbase[tid] = (unsigned int)atomicAdd(&cnt[tid], (int)lcnt[tid]);
    __syncthreads();

    // group into LDS + compute global destinations
#pragma unroll
    for (int i = 0; i < 4; i++) {
        if (v_[i]) {
            unsigned int slot = lbase[b_[i]] + r_[i];
            sg[slot] = p_[i];
            unsigned int gpos = gbase[b_[i]] + r_[i];
            if (gpos < CAPB) {
                sd[slot] = (unsigned int)b_[i] * CAPB + gpos;
            } else {
                sd[slot] = 0xFFFFFFFFu;   // statistically unreachable overflow
                int oi = atomicAdd(ovfn, 1);
                if (oi < OVF_MAX) ovf[oi] = ((unsigned long long)b_[i] << 32) | p_[i];
            }
        }
    }
    __syncthreads();

    // coalesced-run writeout
    unsigned int tot = s_total;
    for (unsigned int t = tid; t < tot; t += 1024) {
        unsigned int d = sd[t];
        if (d != 0xFFFFFFFFu) eidx[d] = sg[t];
    }
}

// ---------------- kernel 4: per-bucket LDS-atomic segment max + agg + BN2 stats --------
// One block per bucket (128 nodes). 64 edge slots x 8 channel lanes = 512 threads.
__global__ __launch_bounds__(512) void k_fine(
    const int* __restrict__ cnt, const unsigned int* __restrict__ eidx,
    const unsigned long long* __restrict__ ovf, const int* __restrict__ ovfn,
    const __half* __restrict__ Bh,
    float* __restrict__ A,             // in: A, out: agg (in place)
    const float* __restrict__ b_msg,
    float* __restrict__ sum2, float* __restrict__ sumsq2)
{
    __shared__ unsigned int smax[128 * 33];  // [node][ch], stride 33 breaks bank aliasing
    __shared__ float sb[32];
    __shared__ float ps[8][32], pq[8][32];
    int tid = threadIdx.x;
    if (tid < 32) sb[tid] = b_msg[tid];
    for (int i = tid; i < 128 * 33; i += 512) smax[i] = 0u;
    __syncthreads();

    int b = blockIdx.x;
    int ne = cnt[b]; if (ne > CAPB) ne = CAPB;
    const unsigned int* eb = eidx + (size_t)b * CAPB;
    int slot = tid >> 3, sub = tid & 7;

    for (int k = slot; k < ne; k += 64) {
        unsigned int p = eb[k];
        int dl = (int)(p >> 17);
        int s  = (int)(p & 0x1FFFFu);
        uint2 hv = *(const uint2*)(Bh + (size_t)s * 32 + sub * 4);
        float x0 = __half2float(__ushort_as_half((unsigned short)(hv.x & 0xFFFFu)));
        float x1 = __half2float(__ushort_as_half((unsigned short)(hv.x >> 16)));
        float x2 = __half2float(__ushort_as_half((unsigned short)(hv.y & 0xFFFFu)));
        float x3 = __half2float(__ushort_as_half((unsigned short)(hv.y >> 16)));
        unsigned int* row = &smax[dl * 33 + sub * 4];
        atomicMax(row + 0, encf(x0));
        atomicMax(row + 1, encf(x1));
        atomicMax(row + 2, encf(x2));
        atomicMax(row + 3, encf(x3));
    }
    int on = *ovfn;
    for (int k = slot; k < on; k += 64) {           // normally on == 0
        unsigned long long oe = ovf[k];
        if ((int)(oe >> 32) == b) {
            unsigned int p = (unsigned int)oe;
            int dl = (int)(p >> 17);
            int s  = (int)(p & 0x1FFFFu);
            uint2 hv = *(const uint2*)(Bh + (size_t)s * 32 + sub * 4);
            float x0 = __half2float(__ushort_as_half((unsigned short)(hv.x & 0xFFFFu)));
            float x1 = __half2float(__ushort_as_half((unsigned short)(hv.x >> 16)));
            float x2 = __half2float(__ushort_as_half((unsigned short)(hv.y & 0xFFFFu)));
            float x3 = __half2float(__ushort_as_half((unsigned short)(hv.y >> 16)));
            unsigned int* row = &smax[dl * 33 + sub * 4];
            atomicMax(row + 0, encf(x0));
            atomicMax(row + 1, encf(x1));
            atomicMax(row + 2, encf(x2));
            atomicMax(row + 3, encf(x3));
        }
    }
    __syncthreads();

    // finalize 128 nodes: agg = A + b_msg + max (or 0); accumulate BN2 stats
    float s0 = 0.f, s1 = 0.f, s2 = 0.f, s3 = 0.f;
    float q0 = 0.f, q1 = 0.f, q2 = 0.f, q3 = 0.f;
#pragma unroll
    for (int i = 0; i < 2; i++) {
        int node = slot + i * 64;
        int n = b * 128 + node;
        if (n < N_NODES) {
            unsigned int k0 = smax[node * 33 + sub * 4 + 0];
            unsigned int k1 = smax[node * 33 + sub * 4 + 1];
            unsigned int k2 = smax[node * 33 + sub * 4 + 2];
            unsigned int k3 = smax[node * 33 + sub * 4 + 3];
            float4* arow = (float4*)(A + (size_t)n * 32 + sub * 4);
            float4 a = *arow;
            float4 agg;
            agg.x = k0 ? (decf(k0) + a.x + sb[sub * 4 + 0]) : 0.f;
            agg.y = k1 ? (decf(k1) + a.y + sb[sub * 4 + 1]) : 0.f;
            agg.z = k2 ? (decf(k2) + a.z + sb[sub * 4 + 2]) : 0.f;
            agg.w = k3 ? (decf(k3) + a.w + sb[sub * 4 + 3]) : 0.f;
            *arow = agg;
            s0 += agg.x; s1 += agg.y; s2 += agg.z; s3 += agg.w;
            q0 += agg.x * agg.x; q1 += agg.y * agg.y;
            q2 += agg.z * agg.z; q3 += agg.w * agg.w;
        }
    }
#pragma unroll
    for (int o = 8; o < 64; o <<= 1) {
        s0 += __shfl_xor(s0, o, 64); s1 += __shfl_xor(s1, o, 64);
        s2 += __shfl_xor(s2, o, 64); s3 += __shfl_xor(s3, o, 64);
        q0 += __shfl_xor(q0, o, 64); q1 += __shfl_xor(q1, o, 64);
        q2 += __shfl_xor(q2, o, 64); q3 += __shfl_xor(q3, o, 64);
    }
    int lane = tid & 63, wid = tid >> 6;
    if (lane < 8) {
        ps[wid][lane * 4 + 0] = s0; ps[wid][lane * 4 + 1] = s1;
        ps[wid][lane * 4 + 2] = s2; ps[wid][lane * 4 + 3] = s3;
        pq[wid][lane * 4 + 0] = q0; pq[wid][lane * 4 + 1] = q1;
        pq[wid][lane * 4 + 2] = q2; pq[wid][lane * 4 + 3] = q3;
    }
    __syncthreads();
    if (tid < 32) {
        float fs = 0.f, fq = 0.f;
#pragma unroll
        for (int w = 0; w < 8; w++) { fs += ps[w][tid]; fq += pq[w][tid]; }
        atomicAdd(&sum2[tid], fs);
        atomicAdd(&sumsq2[tid], fq);
    }
}

// ---------------- kernel 5: BN1-affine + BN2-affine + output head (8 lanes/node) -------
__global__ __launch_bounds__(256) void k_out(
    const float* __restrict__ emb,     // raw (pre-BN1)
    const float* __restrict__ agg,
    const float* __restrict__ g1, const float* __restrict__ be1,
    const float* __restrict__ sum1, const float* __restrict__ sumsq1,
    const float* __restrict__ g2, const float* __restrict__ be2,
    const float* __restrict__ sum2, const float* __restrict__ sumsq2,
    const float* __restrict__ W_o1, const float* __restrict__ b_o1,
    const float* __restrict__ W_o2, const float* __restrict__ b_o2,
    float* __restrict__ out)
{
    __shared__ __align__(16) float sW1[32 * 16];
    __shared__ float sb1o[16], sW2[16];
    __shared__ float sa1[32], sb1c[32], sa2[32], sb2c[32];
    __shared__ float sH[32][33];
    __shared__ float sb2s;
    int tid = threadIdx.x;
    for (int t = tid; t < 512; t += 256) sW1[t] = W_o1[t];
    if (tid < 16) { sW2[tid] = W_o2[tid]; sb1o[tid] = b_o1[tid]; }
    if (tid < 32) {
        float m1 = sum1[tid] / (float)N_NODES;
        float v1 = sumsq1[tid] / (float)N_NODES - m1 * m1;
        float i1 = 1.0f / sqrtf(v1 + BN_EPS);
        float a1 = g1[tid] * i1;
        sa1[tid] = a1;
        sb1c[tid] = be1[tid] - a1 * m1;
        float m2 = sum2[tid] / (float)N_NODES;
        float v2 = sumsq2[tid] / (float)N_NODES - m2 * m2;
        float i2 = 1.0f / sqrtf(v2 + BN_EPS);
        float a2 = g2[tid] * i2;
        sa2[tid] = a2;
        sb2c[tid] = be2[tid] - a2 * m2;
    }
    if (tid == 0) sb2s = b_o2[0];
    __syncthreads();

    int grp = tid >> 3, sub = tid & 7;
    int n = blockIdx.x * 32 + grp;
    int c4 = sub * 4;

    float4 ev = *(const float4*)(emb + (size_t)n * 32 + c4);
    float4 av = *(const float4*)(agg + (size_t)n * 32 + c4);
    sH[grp][c4 + 0] = sa1[c4 + 0] * ev.x + sb1c[c4 + 0] + sa2[c4 + 0] * av.x + sb2c[c4 + 0];
    sH[grp][c4 + 1] = sa1[c4 + 1] * ev.y + sb1c[c4 + 1] + sa2[c4 + 1] * av.y + sb2c[c4 + 1];
    sH[grp][c4 + 2] = sa1[c4 + 2] * ev.z + sb1c[c4 + 2] + sa2[c4 + 2] * av.z + sb2c[c4 + 2];
    sH[grp][c4 + 3] = sa1[c4 + 3] * ev.w + sb1c[c4 + 3] + sa2[c4 + 3] * av.w + sb2c[c4 + 3];
    __syncthreads();   // explicit barrier (R11 lesson)

    int c0 = sub * 2;
    float o0 = sb1o[c0], o1v = sb1o[c0 + 1];
#pragma unroll
    for (int i = 0; i < 32; i++) {
        float x = sH[grp][i];
        o0  += x * sW1[i * 16 + c0];
        o1v += x * sW1[i * 16 + c0 + 1];
    }
    float psum = eluf(o0) * sW2[c0] + eluf(o1v) * sW2[c0 + 1];
    psum += __shfl_xor(psum, 1, 64);
    psum += __shfl_xor(psum, 2, 64);
    psum += __shfl_xor(psum, 4, 64);
    if (sub == 0) out[n] = psum + sb2s;
}

extern "C" void kernel_launch(void* const* d_in, const int* in_sizes, int n_in,
                              void* d_out, int out_size, void* d_ws, size_t ws_size,
                              hipStream_t stream)
{
    const float* x_cont     = (const float*)d_in[0];
    const int*   x_cat      = (const int*)d_in[1];
    const int*   edge_index = (const int*)d_in[2];
    // d_in[3] = batch (unused by reference)
    const float* datanorm   = (const float*)d_in[4];
    const float* W_cont     = (const float*)d_in[5];
    const float* b_cont     = (const float*)d_in[6];
    const float* emb_charge = (const float*)d_in[7];
    const float* emb_pdg    = (const float*)d_in[8];
    const float* W_cat      = (const float*)d_in[9];
    const float* b_cat      = (const float*)d_in[10];
    const float* W_enc      = (const float*)d_in[11];
    const float* b_enc      = (const float*)d_in[12];
    const float* g_all      = (const float*)d_in[13];
    const float* be_all     = (const float*)d_in[14];
    const float* W_msg      = (const float*)d_in[15];
    const float* b_msg      = (const float*)d_in[16];
    const float* g_conv     = (const float*)d_in[17];
    const float* be_conv    = (const float*)d_in[18];
    const float* W_o1       = (const float*)d_in[19];
    const float* b_o1       = (const float*)d_in[20];
    const float* W_o2       = (const float*)d_in[21];
    const float* b_o2       = (const float*)d_in[22];

    const size_t NH = (size_t)N_NODES * 32;
    float* buf_emb = (float*)d_ws;                          // NH floats (raw)
    float* buf_A   = buf_emb + NH;                          // NH floats
    __half* buf_Bh = (__half*)(buf_A + NH);                 // NH halves
    unsigned long long* ovf = (unsigned long long*)(buf_Bh + NH);  // OVF_MAX
    float* stats   = (float*)(ovf + OVF_MAX);               // 256 floats
    int*   cnt     = (int*)(stats + 256);                   // NBUCK
    int*   ovfn    = cnt + NBUCK;                           // 1
    unsigned int* eidx = (unsigned int*)(ovfn + 1);         // NBUCK*CAPB

    float* sum1 = stats,       *sumsq1 = stats + 32;
    float* sum2 = stats + 128, *sumsq2 = stats + 160;

    hipMemsetAsync(stats, 0, (256 + NBUCK + 1) * sizeof(int), stream);

    const int* src = edge_index;
    const int* dst = edge_index + N_EDGES;

    int bb = (N_EDGES + BIN_E - 1) / BIN_E;        // 391

    k_encode<<<NB32, 256, 0, stream>>>(x_cont, x_cat, datanorm, W_cont, b_cont,
                                       emb_charge, emb_pdg, W_cat, b_cat, W_enc, b_enc,
                                       buf_emb, sum1, sumsq1);
    k_bin<<<bb, 1024, 0, stream>>>(src, dst, cnt, eidx, ovf, ovfn);
    k_normAB<<<NB32, 256, 0, stream>>>(buf_emb, W_msg, g_all, be_all, sum1, sumsq1, buf_A, buf_Bh);
    k_fine<<<NBUCK, 512, 0, stream>>>(cnt, eidx, ovf, ovfn, buf_Bh, buf_A, b_msg, sum2, sumsq2);
    k_out<<<NB32, 256, 0, stream>>>(buf_emb, buf_A, g_all, be_all, sum1, sumsq1,
                                    g_conv, be_conv, sum2, sumsq2,
                                    W_o1, b_o1, W_o2, b_o2, (float*)d_out);
}

// Round 14
// 231.124 us; speedup vs baseline: 1.2109x; 1.2109x over previous
//
#include <hip/hip_runtime.h>
#include <hip/hip_fp16.h>
#include <math.h>

#define N_NODES 100000
#define N_EDGES 1600000
#define HID 32
#define BN_EPS 1e-3f
#define NBUCK 782        // buckets of 128 nodes
#define CAPB 2432        // slots per bucket (mean 2046, 8.5 sigma headroom)
#define BIN_E 4096       // edges per binning block
#define OVF_MAX 65536
#define NB32 3125        // node blocks: 32 nodes each

__device__ __forceinline__ float eluf(float x) { return x > 0.f ? x : expm1f(x); }

__device__ __forceinline__ unsigned int encf(float f) {
    unsigned int u = __float_as_uint(f);
    return (u & 0x80000000u) ? ~u : (u | 0x80000000u);
}
__device__ __forceinline__ float decf(unsigned int k) {
    return __uint_as_float((k & 0x80000000u) ? (k & 0x7FFFFFFFu) : ~k);
}

// ---------------- kernel 1: node encoder (8 lanes/node), NO stats ----------------
__global__ __launch_bounds__(256) void k_encode(
    const float* __restrict__ x_cont, const int* __restrict__ x_cat,
    const float* __restrict__ datanorm,
    const float* __restrict__ W_cont, const float* __restrict__ b_cont,
    const float* __restrict__ emb_charge, const float* __restrict__ emb_pdg,
    const float* __restrict__ W_cat, const float* __restrict__ b_cat,
    const float* __restrict__ W_enc, const float* __restrict__ b_enc,
    float* __restrict__ emb_out)
{
    __shared__ __align__(16) float sWc[6 * 16];
    __shared__ __align__(16) float sWcat[16 * 16];
    __shared__ __align__(16) float sWenc[32 * 32];
    __shared__ float sbc[16], sbcat[16], sbenc[32];
    __shared__ float sdn[6], sech[3 * 8], sepd[7 * 8];
    __shared__ float sIN[32][33];

    int tid = threadIdx.x;
    for (int t = tid; t < 96; t += 256) sWc[t] = W_cont[t];
    sWcat[tid] = W_cat[tid];
    for (int t = tid; t < 1024; t += 256) sWenc[t] = W_enc[t];
    if (tid < 16) { sbc[tid] = b_cont[tid]; sbcat[tid] = b_cat[tid]; }
    if (tid < 32) sbenc[tid] = b_enc[tid];
    if (tid < 6)  sdn[tid] = datanorm[tid];
    if (tid < 24) sech[tid] = emb_charge[tid];
    if (tid < 56) sepd[tid] = emb_pdg[tid];
    __syncthreads();

    int grp = tid >> 3;
    int sub = tid & 7;
    int n = blockIdx.x * 32 + grp;

    float xc[6];
#pragma unroll
    for (int i = 0; i < 6; i++) xc[i] = x_cont[n * 6 + i] * sdn[i];
    int pdg = x_cat[n * 2 + 0], chg = x_cat[n * 2 + 1];
    int p = pdg < 0 ? -pdg : pdg;
    int pidx;
    switch (p) {
        case 1: pidx = 0; break; case 2: pidx = 1; break;
        case 11: pidx = 2; break; case 13: pidx = 3; break;
        case 22: pidx = 4; break; case 130: pidx = 5; break;
        case 211: pidx = 6; break; default: pidx = 0; break;
    }

    int c0 = sub * 2;
    float a0 = sbc[c0], a1 = sbc[c0 + 1];
#pragma unroll
    for (int i = 0; i < 6; i++) {
        a0 += xc[i] * sWc[i * 16 + c0];
        a1 += xc[i] * sWc[i * 16 + c0 + 1];
    }
    float cont0 = eluf(a0), cont1 = eluf(a1);

    float cin[16];
#pragma unroll
    for (int k = 0; k < 8; k++) cin[k] = sech[(chg + 1) * 8 + k];
#pragma unroll
    for (int k = 0; k < 8; k++) cin[8 + k] = sepd[pidx * 8 + k];
    float b0 = sbcat[c0], b1 = sbcat[c0 + 1];
#pragma unroll
    for (int i = 0; i < 16; i++) {
        b0 += cin[i] * sWcat[i * 16 + c0];
        b1 += cin[i] * sWcat[i * 16 + c0 + 1];
    }
    float cat0 = eluf(b0), cat1 = eluf(b1);

    sIN[grp][c0 + 0] = cat0;  sIN[grp][c0 + 1] = cat1;
    sIN[grp][16 + c0 + 0] = cont0; sIN[grp][16 + c0 + 1] = cont1;
    __syncthreads();   // LDS exchange barrier (R11 lesson)

    int c4 = sub * 4;
    float e0 = sbenc[c4], e1 = sbenc[c4 + 1], e2 = sbenc[c4 + 2], e3 = sbenc[c4 + 3];
#pragma unroll
    for (int i = 0; i < 32; i++) {
        float x = sIN[grp][i];
        const float4 w = *(const float4*)&sWenc[i * 32 + c4];
        e0 += x * w.x; e1 += x * w.y; e2 += x * w.z; e3 += x * w.w;
    }
    *(float4*)(emb_out + (size_t)n * 32 + c4) =
        make_float4(eluf(e0), eluf(e1), eluf(e2), eluf(e3));
}

// ---------------- kernel 1b: BN1 stats over emb (few blocks -> few atomics) ------------
__global__ __launch_bounds__(256) void k_stats1(
    const float* __restrict__ emb, float* __restrict__ sum1, float* __restrict__ sumsq1)
{
    __shared__ float rs[256], rq[256];
    int tid = threadIdx.x;
    int c = tid & 31;              // channel
    int g = tid >> 5;              // node sub-slot 0..7
    float s = 0.f, q = 0.f;
    for (int base = blockIdx.x * 8; base < N_NODES; base += gridDim.x * 8) {
        int n = base + g;
        if (n < N_NODES) {
            float v = emb[(size_t)n * 32 + c];
            s += v; q += v * v;
        }
    }
    rs[tid] = s; rq[tid] = q;
    __syncthreads();
    if (tid < 32) {
        float fs = 0.f, fq = 0.f;
#pragma unroll
        for (int w = 0; w < 8; w++) { fs += rs[tid + w * 32]; fq += rq[tid + w * 32]; }
        atomicAdd(&sum1[tid], fs);
        atomicAdd(&sumsq1[tid], fq);
    }
}

// ---------------- kernel 2: BN1 affine -> A [fp32], B [fp16] (8 lanes/node) ------------
__global__ __launch_bounds__(256) void k_normAB(
    const float* __restrict__ emb,
    const float* __restrict__ W_msg,
    const float* __restrict__ g, const float* __restrict__ be,
    const float* __restrict__ sum1, const float* __restrict__ sumsq1,
    float* __restrict__ A, __half* __restrict__ Bh)
{
    __shared__ __align__(16) float sWA[32 * 32];
    __shared__ __align__(16) float sWB[32 * 32];
    __shared__ float sa1[32], sb1[32];
    __shared__ float sE[32][33];
    int tid = threadIdx.x;
    for (int t = tid; t < 1024; t += 256) {
        float w0 = W_msg[t];
        float w1 = W_msg[1024 + t];
        sWA[t] = w0 - w1;
        sWB[t] = w1;
    }
    if (tid < 32) {
        float m = sum1[tid] / (float)N_NODES;
        float v = sumsq1[tid] / (float)N_NODES - m * m;
        float i1 = 1.0f / sqrtf(v + BN_EPS);
        float a1 = g[tid] * i1;
        sa1[tid] = a1;
        sb1[tid] = be[tid] - a1 * m;
    }
    __syncthreads();

    int grp = tid >> 3, sub = tid & 7;
    int n = blockIdx.x * 32 + grp;
    int c4 = sub * 4;

    float4 ev = *(const float4*)(emb + (size_t)n * 32 + c4);
    sE[grp][c4 + 0] = sa1[c4 + 0] * ev.x + sb1[c4 + 0];
    sE[grp][c4 + 1] = sa1[c4 + 1] * ev.y + sb1[c4 + 1];
    sE[grp][c4 + 2] = sa1[c4 + 2] * ev.z + sb1[c4 + 2];
    sE[grp][c4 + 3] = sa1[c4 + 3] * ev.w + sb1[c4 + 3];
    __syncthreads();   // LDS exchange barrier (R11 lesson)

    float a0 = 0.f, a1 = 0.f, a2 = 0.f, a3 = 0.f;
    float b0 = 0.f, b1 = 0.f, b2 = 0.f, b3 = 0.f;
#pragma unroll
    for (int i = 0; i < 32; i++) {
        float x = sE[grp][i];
        const float4 wa = *(const float4*)&sWA[i * 32 + c4];
        const float4 wb = *(const float4*)&sWB[i * 32 + c4];
        a0 += x * wa.x; a1 += x * wa.y; a2 += x * wa.z; a3 += x * wa.w;
        b0 += x * wb.x; b1 += x * wb.y; b2 += x * wb.z; b3 += x * wb.w;
    }
    *(float4*)(A + (size_t)n * 32 + c4) = make_float4(a0, a1, a2, a3);

    unsigned int lo = ((unsigned int)__half_as_ushort(__float2half_rn(b1)) << 16)
                    | (unsigned int)__half_as_ushort(__float2half_rn(b0));
    unsigned int hi = ((unsigned int)__half_as_ushort(__float2half_rn(b3)) << 16)
                    | (unsigned int)__half_as_ushort(__float2half_rn(b2));
    *(uint2*)(Bh + (size_t)n * 32 + c4) = make_uint2(lo, hi);
}

// ---------------- kernel 3: LDS-staged multisplit binning of edges by dst bucket -------
__global__ __launch_bounds__(1024) void k_bin(
    const int* __restrict__ src, const int* __restrict__ dst,
    int* __restrict__ cnt, unsigned int* __restrict__ eidx,
    unsigned long long* __restrict__ ovf, int* __restrict__ ovfn)
{
    __shared__ unsigned int lcnt[NBUCK];
    __shared__ unsigned int lbase[NBUCK];
    __shared__ unsigned int gbase[NBUCK];
    __shared__ unsigned int sc[1024];
    __shared__ unsigned int sg[BIN_E];
    __shared__ unsigned int sd[BIN_E];
    __shared__ unsigned int s_total;

    int tid = threadIdx.x;
    for (int i = tid; i < NBUCK; i += 1024) lcnt[i] = 0;
    __syncthreads();

    int e0 = blockIdx.x * BIN_E;
    int b_[4]; unsigned int p_[4], r_[4]; bool v_[4];
#pragma unroll
    for (int i = 0; i < 4; i++) {
        int e = e0 + i * 1024 + tid;
        v_[i] = (e < N_EDGES);
        b_[i] = 0; p_[i] = 0; r_[i] = 0;
        if (v_[i]) {
            int d = dst[e], s = src[e];
            b_[i] = d >> 7;
            p_[i] = ((unsigned int)(d & 127) << 17) | (unsigned int)s;
            r_[i] = atomicAdd(&lcnt[b_[i]], 1u);
        }
    }
    __syncthreads();

    sc[tid] = (tid < NBUCK) ? lcnt[tid] : 0;
    __syncthreads();
    for (int o = 1; o < 1024; o <<= 1) {
        unsigned int u = (tid >= o) ? sc[tid - o] : 0;
        __syncthreads();
        sc[tid] += u;
        __syncthreads();
    }
    if (tid < NBUCK) lbase[tid] = sc[tid] - lcnt[tid];
    if (tid == 0) s_total = sc[1023];
    if (tid < NBUCK && lcnt[tid] > 0)
        gbase[tid] = (unsigned int)atomicAdd(&cnt[tid], (int)lcnt[tid]);
    __syncthreads();

#pragma unroll
    for (int i = 0; i < 4; i++) {
        if (v_[i]) {
            unsigned int slot = lbase[b_[i]] + r_[i];
            sg[slot] = p_[i];
            unsigned int gpos = gbase[b_[i]] + r_[i];
            if (gpos < CAPB) {
                sd[slot] = (unsigned int)b_[i] * CAPB + gpos;
            } else {
                sd[slot] = 0xFFFFFFFFu;
                int oi = atomicAdd(ovfn, 1);
                if (oi < OVF_MAX) ovf[oi] = ((unsigned long long)b_[i] << 32) | p_[i];
            }
        }
    }
    __syncthreads();

    unsigned int tot = s_total;
    for (unsigned int t = tid; t < tot; t += 1024) {
        unsigned int d = sd[t];
        if (d != 0xFFFFFFFFu) eidx[d] = sg[t];
    }
}

// ---------------- kernel 4: per-bucket LDS-atomic segment max + agg; partial BN2 -------
__global__ __launch_bounds__(512) void k_fine(
    const int* __restrict__ cnt, const unsigned int* __restrict__ eidx,
    const unsigned long long* __restrict__ ovf, const int* __restrict__ ovfn,
    const __half* __restrict__ Bh,
    float* __restrict__ A,             // in: A, out: agg (in place)
    const float* __restrict__ b_msg,
    float* __restrict__ pc2s, float* __restrict__ pc2q)  // [NBUCK][32] partials
{
    __shared__ unsigned int smax[128 * 33];
    __shared__ float sb[32];
    __shared__ float ps[8][32], pq[8][32];
    int tid = threadIdx.x;
    if (tid < 32) sb[tid] = b_msg[tid];
    for (int i = tid; i < 128 * 33; i += 512) smax[i] = 0u;
    __syncthreads();

    int b = blockIdx.x;
    int ne = cnt[b]; if (ne > CAPB) ne = CAPB;
    const unsigned int* eb = eidx + (size_t)b * CAPB;
    int slot = tid >> 3, sub = tid & 7;

    for (int k = slot; k < ne; k += 64) {
        unsigned int p = eb[k];
        int dl = (int)(p >> 17);
        int s  = (int)(p & 0x1FFFFu);
        uint2 hv = *(const uint2*)(Bh + (size_t)s * 32 + sub * 4);
        float x0 = __half2float(__ushort_as_half((unsigned short)(hv.x & 0xFFFFu)));
        float x1 = __half2float(__ushort_as_half((unsigned short)(hv.x >> 16)));
        float x2 = __half2float(__ushort_as_half((unsigned short)(hv.y & 0xFFFFu)));
        float x3 = __half2float(__ushort_as_half((unsigned short)(hv.y >> 16)));
        unsigned int* row = &smax[dl * 33 + sub * 4];
        atomicMax(row + 0, encf(x0));
        atomicMax(row + 1, encf(x1));
        atomicMax(row + 2, encf(x2));
        atomicMax(row + 3, encf(x3));
    }
    int on = *ovfn;
    for (int k = slot; k < on; k += 64) {           // normally on == 0
        unsigned long long oe = ovf[k];
        if ((int)(oe >> 32) == b) {
            unsigned int p = (unsigned int)oe;
            int dl = (int)(p >> 17);
            int s  = (int)(p & 0x1FFFFu);
            uint2 hv = *(const uint2*)(Bh + (size_t)s * 32 + sub * 4);
            float x0 = __half2float(__ushort_as_half((unsigned short)(hv.x & 0xFFFFu)));
            float x1 = __half2float(__ushort_as_half((unsigned short)(hv.x >> 16)));
            float x2 = __half2float(__ushort_as_half((unsigned short)(hv.y & 0xFFFFu)));
            float x3 = __half2float(__ushort_as_half((unsigned short)(hv.y >> 16)));
            unsigned int* row = &smax[dl * 33 + sub * 4];
            atomicMax(row + 0, encf(x0));
            atomicMax(row + 1, encf(x1));
            atomicMax(row + 2, encf(x2));
            atomicMax(row + 3, encf(x3));
        }
    }
    __syncthreads();

    float s0 = 0.f, s1 = 0.f, s2 = 0.f, s3 = 0.f;
    float q0 = 0.f, q1 = 0.f, q2 = 0.f, q3 = 0.f;
#pragma unroll
    for (int i = 0; i < 2; i++) {
        int node = slot + i * 64;
        int n = b * 128 + node;
        if (n < N_NODES) {
            unsigned int k0 = smax[node * 33 + sub * 4 + 0];
            unsigned int k1 = smax[node * 33 + sub * 4 + 1];
            unsigned int k2 = smax[node * 33 + sub * 4 + 2];
            unsigned int k3 = smax[node * 33 + sub * 4 + 3];
            float4* arow = (float4*)(A + (size_t)n * 32 + sub * 4);
            float4 a = *arow;
            float4 agg;
            agg.x = k0 ? (decf(k0) + a.x + sb[sub * 4 + 0]) : 0.f;
            agg.y = k1 ? (decf(k1) + a.y + sb[sub * 4 + 1]) : 0.f;
            agg.z = k2 ? (decf(k2) + a.z + sb[sub * 4 + 2]) : 0.f;
            agg.w = k3 ? (decf(k3) + a.w + sb[sub * 4 + 3]) : 0.f;
            *arow = agg;
            s0 += agg.x; s1 += agg.y; s2 += agg.z; s3 += agg.w;
            q0 += agg.x * agg.x; q1 += agg.y * agg.y;
            q2 += agg.z * agg.z; q3 += agg.w * agg.w;
        }
    }
#pragma unroll
    for (int o = 8; o < 64; o <<= 1) {
        s0 += __shfl_xor(s0, o, 64); s1 += __shfl_xor(s1, o, 64);
        s2 += __shfl_xor(s2, o, 64); s3 += __shfl_xor(s3, o, 64);
        q0 += __shfl_xor(q0, o, 64); q1 += __shfl_xor(q1, o, 64);
        q2 += __shfl_xor(q2, o, 64); q3 += __shfl_xor(q3, o, 64);
    }
    int lane = tid & 63, wid = tid >> 6;
    if (lane < 8) {
        ps[wid][lane * 4 + 0] = s0; ps[wid][lane * 4 + 1] = s1;
        ps[wid][lane * 4 + 2] = s2; ps[wid][lane * 4 + 3] = s3;
        pq[wid][lane * 4 + 0] = q0; pq[wid][lane * 4 + 1] = q1;
        pq[wid][lane * 4 + 2] = q2; pq[wid][lane * 4 + 3] = q3;
    }
    __syncthreads();
    if (tid < 32) {
        float fs = 0.f, fq = 0.f;
#pragma unroll
        for (int w = 0; w < 8; w++) { fs += ps[w][tid]; fq += pq[w][tid]; }
        pc2s[(size_t)b * 32 + tid] = fs;    // non-atomic partial write
        pc2q[(size_t)b * 32 + tid] = fq;
    }
}

// ---------------- kernel 4b: reduce BN2 partials (1 block) ----------------
__global__ __launch_bounds__(1024) void k_red2(
    const float* __restrict__ pc2s, const float* __restrict__ pc2q,
    float* __restrict__ sum2, float* __restrict__ sumsq2)
{
    __shared__ float rs[32][33], rq[32][33];
    int tid = threadIdx.x;
    int c = tid & 31, r0 = tid >> 5;   // 32 row-strides
    float s = 0.f, q = 0.f;
    for (int r = r0; r < NBUCK; r += 32) {
        s += pc2s[(size_t)r * 32 + c];
        q += pc2q[(size_t)r * 32 + c];
    }
    rs[r0][c] = s; rq[r0][c] = q;
    __syncthreads();
    if (tid < 32) {
        float fs = 0.f, fq = 0.f;
#pragma unroll
        for (int r = 0; r < 32; r++) { fs += rs[r][tid]; fq += rq[r][tid]; }
        sum2[tid] = fs;
        sumsq2[tid] = fq;
    }
}

// ---------------- kernel 5: BN1-affine + BN2-affine + output head (8 lanes/node) -------
__global__ __launch_bounds__(256) void k_out(
    const float* __restrict__ emb,
    const float* __restrict__ agg,
    const float* __restrict__ g1, const float* __restrict__ be1,
    const float* __restrict__ sum1, const float* __restrict__ sumsq1,
    const float* __restrict__ g2, const float* __restrict__ be2,
    const float* __restrict__ sum2, const float* __restrict__ sumsq2,
    const float* __restrict__ W_o1, const float* __restrict__ b_o1,
    const float* __restrict__ W_o2, const float* __restrict__ b_o2,
    float* __restrict__ out)
{
    __shared__ __align__(16) float sW1[32 * 16];
    __shared__ float sb1o[16], sW2[16];
    __shared__ float sa1[32], sb1c[32], sa2[32], sb2c[32];
    __shared__ float sH[32][33];
    __shared__ float sb2s;
    int tid = threadIdx.x;
    for (int t = tid; t < 512; t += 256) sW1[t] = W_o1[t];
    if (tid < 16) { sW2[tid] = W_o2[tid]; sb1o[tid] = b_o1[tid]; }
    if (tid < 32) {
        float m1 = sum1[tid] / (float)N_NODES;
        float v1 = sumsq1[tid] / (float)N_NODES - m1 * m1;
        float i1 = 1.0f / sqrtf(v1 + BN_EPS);
        float a1 = g1[tid] * i1;
        sa1[tid] = a1;
        sb1c[tid] = be1[tid] - a1 * m1;
        float m2 = sum2[tid] / (float)N_NODES;
        float v2 = sumsq2[tid] / (float)N_NODES - m2 * m2;
        float i2 = 1.0f / sqrtf(v2 + BN_EPS);
        float a2 = g2[tid] * i2;
        sa2[tid] = a2;
        sb2c[tid] = be2[tid] - a2 * m2;
    }
    if (tid == 0) sb2s = b_o2[0];
    __syncthreads();

    int grp = tid >> 3, sub = tid & 7;
    int n = blockIdx.x * 32 + grp;
    int c4 = sub * 4;

    float4 ev = *(const float4*)(emb + (size_t)n * 32 + c4);
    float4 av = *(const float4*)(agg + (size_t)n * 32 + c4);
    sH[grp][c4 + 0] = sa1[c4 + 0] * ev.x + sb1c[c4 + 0] + sa2[c4 + 0] * av.x + sb2c[c4 + 0];
    sH[grp][c4 + 1] = sa1[c4 + 1] * ev.y + sb1c[c4 + 1] + sa2[c4 + 1] * av.y + sb2c[c4 + 1];
    sH[grp][c4 + 2] = sa1[c4 + 2] * ev.z + sb1c[c4 + 2] + sa2[c4 + 2] * av.z + sb2c[c4 + 2];
    sH[grp][c4 + 3] = sa1[c4 + 3] * ev.w + sb1c[c4 + 3] + sa2[c4 + 3] * av.w + sb2c[c4 + 3];
    __syncthreads();   // LDS exchange barrier (R11 lesson)

    int c0 = sub * 2;
    float o0 = sb1o[c0], o1v = sb1o[c0 + 1];
#pragma unroll
    for (int i = 0; i < 32; i++) {
        float x = sH[grp][i];
        o0  += x * sW1[i * 16 + c0];
        o1v += x * sW1[i * 16 + c0 + 1];
    }
    float psum = eluf(o0) * sW2[c0] + eluf(o1v) * sW2[c0 + 1];
    psum += __shfl_xor(psum, 1, 64);
    psum += __shfl_xor(psum, 2, 64);
    psum += __shfl_xor(psum, 4, 64);
    if (sub == 0) out[n] = psum + sb2s;
}

extern "C" void kernel_launch(void* const* d_in, const int* in_sizes, int n_in,
                              void* d_out, int out_size, void* d_ws, size_t ws_size,
                              hipStream_t stream)
{
    const float* x_cont     = (const float*)d_in[0];
    const int*   x_cat      = (const int*)d_in[1];
    const int*   edge_index = (const int*)d_in[2];
    const float* datanorm   = (const float*)d_in[4];
    const float* W_cont     = (const float*)d_in[5];
    const float* b_cont     = (const float*)d_in[6];
    const float* emb_charge = (const float*)d_in[7];
    const float* emb_pdg    = (const float*)d_in[8];
    const float* W_cat      = (const float*)d_in[9];
    const float* b_cat      = (const float*)d_in[10];
    const float* W_enc      = (const float*)d_in[11];
    const float* b_enc      = (const float*)d_in[12];
    const float* g_all      = (const float*)d_in[13];
    const float* be_all     = (const float*)d_in[14];
    const float* W_msg      = (const float*)d_in[15];
    const float* b_msg      = (const float*)d_in[16];
    const float* g_conv     = (const float*)d_in[17];
    const float* be_conv    = (const float*)d_in[18];
    const float* W_o1       = (const float*)d_in[19];
    const float* b_o1       = (const float*)d_in[20];
    const float* W_o2       = (const float*)d_in[21];
    const float* b_o2       = (const float*)d_in[22];

    const size_t NH = (size_t)N_NODES * 32;
    float* buf_emb = (float*)d_ws;                          // NH floats (raw)
    float* buf_A   = buf_emb + NH;                          // NH floats
    __half* buf_Bh = (__half*)(buf_A + NH);                 // NH halves
    unsigned long long* ovf = (unsigned long long*)(buf_Bh + NH);  // OVF_MAX
    float* stats   = (float*)(ovf + OVF_MAX);               // 256 floats
    float* pc2s    = stats + 256;                           // NBUCK*32
    float* pc2q    = pc2s + (size_t)NBUCK * 32;             // NBUCK*32
    int*   cnt     = (int*)(pc2q + (size_t)NBUCK * 32);     // NBUCK
    int*   ovfn    = cnt + NBUCK;                           // 1
    unsigned int* eidx = (unsigned int*)(ovfn + 1);         // NBUCK*CAPB

    float* sum1 = stats,       *sumsq1 = stats + 32;
    float* sum2 = stats + 128, *sumsq2 = stats + 160;

    hipMemsetAsync(stats, 0, 256 * sizeof(float), stream);
    hipMemsetAsync(cnt, 0, (NBUCK + 1) * sizeof(int), stream);

    const int* src = edge_index;
    const int* dst = edge_index + N_EDGES;

    int bb = (N_EDGES + BIN_E - 1) / BIN_E;        // 391

    k_encode<<<NB32, 256, 0, stream>>>(x_cont, x_cat, datanorm, W_cont, b_cont,
                                       emb_charge, emb_pdg, W_cat, b_cat, W_enc, b_enc,
                                       buf_emb);
    k_stats1<<<256, 256, 0, stream>>>(buf_emb, sum1, sumsq1);
    k_bin<<<bb, 1024, 0, stream>>>(src, dst, cnt, eidx, ovf, ovfn);
    k_normAB<<<NB32, 256, 0, stream>>>(buf_emb, W_msg, g_all, be_all, sum1, sumsq1, buf_A, buf_Bh);
    k_fine<<<NBUCK, 512, 0, stream>>>(cnt, eidx, ovf, ovfn, buf_Bh, buf_A, b_msg, pc2s, pc2q);
    k_red2<<<1, 1024, 0, stream>>>(pc2s, pc2q, sum2, sumsq2);
    k_out<<<NB32, 256, 0, stream>>>(buf_emb, buf_A, g_all, be_all, sum1, sumsq1,
                                    g_conv, be_conv, sum2, sumsq2,
                                    W_o1, b_o1, W_o2, b_o2, (float*)d_out);
}

// Round 15
// 209.072 us; speedup vs baseline: 1.3386x; 1.1055x over previous
//
#include <hip/hip_runtime.h>
#include <hip/hip_fp16.h>
#include <math.h>

#define N_NODES 100000
#define N_EDGES 1600000
#define HID 32
#define BN_EPS 1e-3f
#define NBUCK 782        // buckets of 128 nodes
#define CAPB 2432        // slots per bucket (mean 2046, 8.5 sigma headroom)
#define BIN_E 4096       // edges per binning block
#define BIN_BLKS 391     // ceil(E / BIN_E)
#define STAT_BLKS 256
#define OVF_MAX 65536
#define NB32 3125        // node blocks: 32 nodes each

__device__ __forceinline__ float eluf(float x) { return x > 0.f ? x : expm1f(x); }

__device__ __forceinline__ unsigned int encf(float f) {
    unsigned int u = __float_as_uint(f);
    return (u & 0x80000000u) ? ~u : (u | 0x80000000u);
}
__device__ __forceinline__ float decf(unsigned int k) {
    return __uint_as_float((k & 0x80000000u) ? (k & 0x7FFFFFFFu) : ~k);
}

// ---------------- kernel 1: node encoder (8 lanes/node), NO stats ----------------
__global__ __launch_bounds__(256) void k_encode(
    const float* __restrict__ x_cont, const int* __restrict__ x_cat,
    const float* __restrict__ datanorm,
    const float* __restrict__ W_cont, const float* __restrict__ b_cont,
    const float* __restrict__ emb_charge, const float* __restrict__ emb_pdg,
    const float* __restrict__ W_cat, const float* __restrict__ b_cat,
    const float* __restrict__ W_enc, const float* __restrict__ b_enc,
    float* __restrict__ emb_out)
{
    __shared__ __align__(16) float sWc[6 * 16];
    __shared__ __align__(16) float sWcat[16 * 16];
    __shared__ __align__(16) float sWenc[32 * 32];
    __shared__ float sbc[16], sbcat[16], sbenc[32];
    __shared__ float sdn[6], sech[3 * 8], sepd[7 * 8];
    __shared__ float sIN[32][33];

    int tid = threadIdx.x;
    for (int t = tid; t < 96; t += 256) sWc[t] = W_cont[t];
    sWcat[tid] = W_cat[tid];
    for (int t = tid; t < 1024; t += 256) sWenc[t] = W_enc[t];
    if (tid < 16) { sbc[tid] = b_cont[tid]; sbcat[tid] = b_cat[tid]; }
    if (tid < 32) sbenc[tid] = b_enc[tid];
    if (tid < 6)  sdn[tid] = datanorm[tid];
    if (tid < 24) sech[tid] = emb_charge[tid];
    if (tid < 56) sepd[tid] = emb_pdg[tid];
    __syncthreads();

    int grp = tid >> 3;
    int sub = tid & 7;
    int n = blockIdx.x * 32 + grp;

    float xc[6];
#pragma unroll
    for (int i = 0; i < 6; i++) xc[i] = x_cont[n * 6 + i] * sdn[i];
    int pdg = x_cat[n * 2 + 0], chg = x_cat[n * 2 + 1];
    int p = pdg < 0 ? -pdg : pdg;
    int pidx;
    switch (p) {
        case 1: pidx = 0; break; case 2: pidx = 1; break;
        case 11: pidx = 2; break; case 13: pidx = 3; break;
        case 22: pidx = 4; break; case 130: pidx = 5; break;
        case 211: pidx = 6; break; default: pidx = 0; break;
    }

    int c0 = sub * 2;
    float a0 = sbc[c0], a1 = sbc[c0 + 1];
#pragma unroll
    for (int i = 0; i < 6; i++) {
        a0 += xc[i] * sWc[i * 16 + c0];
        a1 += xc[i] * sWc[i * 16 + c0 + 1];
    }
    float cont0 = eluf(a0), cont1 = eluf(a1);

    float cin[16];
#pragma unroll
    for (int k = 0; k < 8; k++) cin[k] = sech[(chg + 1) * 8 + k];
#pragma unroll
    for (int k = 0; k < 8; k++) cin[8 + k] = sepd[pidx * 8 + k];
    float b0 = sbcat[c0], b1 = sbcat[c0 + 1];
#pragma unroll
    for (int i = 0; i < 16; i++) {
        b0 += cin[i] * sWcat[i * 16 + c0];
        b1 += cin[i] * sWcat[i * 16 + c0 + 1];
    }
    float cat0 = eluf(b0), cat1 = eluf(b1);

    sIN[grp][c0 + 0] = cat0;  sIN[grp][c0 + 1] = cat1;
    sIN[grp][16 + c0 + 0] = cont0; sIN[grp][16 + c0 + 1] = cont1;
    __syncthreads();   // LDS exchange barrier (R11 lesson)

    int c4 = sub * 4;
    float e0 = sbenc[c4], e1 = sbenc[c4 + 1], e2 = sbenc[c4 + 2], e3 = sbenc[c4 + 3];
#pragma unroll
    for (int i = 0; i < 32; i++) {
        float x = sIN[grp][i];
        const float4 w = *(const float4*)&sWenc[i * 32 + c4];
        e0 += x * w.x; e1 += x * w.y; e2 += x * w.z; e3 += x * w.w;
    }
    *(float4*)(emb_out + (size_t)n * 32 + c4) =
        make_float4(eluf(e0), eluf(e1), eluf(e2), eluf(e3));
}

// ---------------- kernel 2 (fused): blocks [0,391) bin edges; [391,647) BN1 stats ------
__global__ __launch_bounds__(1024) void k_statbin(
    const int* __restrict__ src, const int* __restrict__ dst,
    int* __restrict__ cnt, unsigned int* __restrict__ eidx,
    unsigned long long* __restrict__ ovf, int* __restrict__ ovfn,
    const float* __restrict__ emb, float* __restrict__ sum1, float* __restrict__ sumsq1)
{
    __shared__ unsigned int lcnt[NBUCK];
    __shared__ unsigned int lbase[NBUCK];
    __shared__ unsigned int gbase[NBUCK];
    __shared__ unsigned int sc[1024];
    __shared__ unsigned int sg[BIN_E];
    __shared__ unsigned int sd[BIN_E];
    __shared__ unsigned int s_total;

    int tid = threadIdx.x;

    if (blockIdx.x >= BIN_BLKS) {
        // ---- BN1 stats part (256 blocks, few atomics) ----
        float* rs = (float*)sg;        // reuse LDS
        float* rq = (float*)sd;
        int c = tid & 31;              // channel
        int g = tid >> 5;              // node sub-slot 0..31
        int sblk = blockIdx.x - BIN_BLKS;
        float s = 0.f, q = 0.f;
        for (int base = sblk * 32; base < N_NODES; base += STAT_BLKS * 32) {
            int n = base + g;
            if (n < N_NODES) {
                float v = emb[(size_t)n * 32 + c];
                s += v; q += v * v;
            }
        }
        rs[tid] = s; rq[tid] = q;
        __syncthreads();
        if (tid < 32) {
            float fs = 0.f, fq = 0.f;
#pragma unroll
            for (int w = 0; w < 32; w++) { fs += rs[tid + w * 32]; fq += rq[tid + w * 32]; }
            atomicAdd(&sum1[tid], fs);
            atomicAdd(&sumsq1[tid], fq);
        }
        return;
    }

    // ---- multisplit bin part (391 blocks) ----
    for (int i = tid; i < NBUCK; i += 1024) lcnt[i] = 0;
    __syncthreads();

    int e0 = blockIdx.x * BIN_E;
    int b_[4]; unsigned int p_[4], r_[4]; bool v_[4];
#pragma unroll
    for (int i = 0; i < 4; i++) {
        int e = e0 + i * 1024 + tid;
        v_[i] = (e < N_EDGES);
        b_[i] = 0; p_[i] = 0; r_[i] = 0;
        if (v_[i]) {
            int d = dst[e], s = src[e];
            b_[i] = d >> 7;
            p_[i] = ((unsigned int)(d & 127) << 17) | (unsigned int)s;
            r_[i] = atomicAdd(&lcnt[b_[i]], 1u);
        }
    }
    __syncthreads();

    sc[tid] = (tid < NBUCK) ? lcnt[tid] : 0;
    __syncthreads();
    for (int o = 1; o < 1024; o <<= 1) {
        unsigned int u = (tid >= o) ? sc[tid - o] : 0;
        __syncthreads();
        sc[tid] += u;
        __syncthreads();
    }
    if (tid < NBUCK) lbase[tid] = sc[tid] - lcnt[tid];
    if (tid == 0) s_total = sc[1023];
    if (tid < NBUCK && lcnt[tid] > 0)
        gbase[tid] = (unsigned int)atomicAdd(&cnt[tid], (int)lcnt[tid]);
    __syncthreads();

#pragma unroll
    for (int i = 0; i < 4; i++) {
        if (v_[i]) {
            unsigned int slot = lbase[b_[i]] + r_[i];
            sg[slot] = p_[i];
            unsigned int gpos = gbase[b_[i]] + r_[i];
            if (gpos < CAPB) {
                sd[slot] = (unsigned int)b_[i] * CAPB + gpos;
            } else {
                sd[slot] = 0xFFFFFFFFu;
                int oi = atomicAdd(ovfn, 1);
                if (oi < OVF_MAX) ovf[oi] = ((unsigned long long)b_[i] << 32) | p_[i];
            }
        }
    }
    __syncthreads();

    unsigned int tot = s_total;
    for (unsigned int t = tid; t < tot; t += 1024) {
        unsigned int d = sd[t];
        if (d != 0xFFFFFFFFu) eidx[d] = sg[t];
    }
}

// ---------------- kernel 3: BN1 affine -> A [fp32], B [fp16] (8 lanes/node) ------------
__global__ __launch_bounds__(256) void k_normAB(
    const float* __restrict__ emb,
    const float* __restrict__ W_msg,
    const float* __restrict__ g, const float* __restrict__ be,
    const float* __restrict__ sum1, const float* __restrict__ sumsq1,
    float* __restrict__ A, __half* __restrict__ Bh)
{
    __shared__ __align__(16) float sWA[32 * 32];
    __shared__ __align__(16) float sWB[32 * 32];
    __shared__ float sa1[32], sb1[32];
    __shared__ float sE[32][33];
    int tid = threadIdx.x;
    for (int t = tid; t < 1024; t += 256) {
        float w0 = W_msg[t];
        float w1 = W_msg[1024 + t];
        sWA[t] = w0 - w1;
        sWB[t] = w1;
    }
    if (tid < 32) {
        float m = sum1[tid] / (float)N_NODES;
        float v = sumsq1[tid] / (float)N_NODES - m * m;
        float i1 = 1.0f / sqrtf(v + BN_EPS);
        float a1 = g[tid] * i1;
        sa1[tid] = a1;
        sb1[tid] = be[tid] - a1 * m;
    }
    __syncthreads();

    int grp = tid >> 3, sub = tid & 7;
    int n = blockIdx.x * 32 + grp;
    int c4 = sub * 4;

    float4 ev = *(const float4*)(emb + (size_t)n * 32 + c4);
    sE[grp][c4 + 0] = sa1[c4 + 0] * ev.x + sb1[c4 + 0];
    sE[grp][c4 + 1] = sa1[c4 + 1] * ev.y + sb1[c4 + 1];
    sE[grp][c4 + 2] = sa1[c4 + 2] * ev.z + sb1[c4 + 2];
    sE[grp][c4 + 3] = sa1[c4 + 3] * ev.w + sb1[c4 + 3];
    __syncthreads();   // LDS exchange barrier (R11 lesson)

    float a0 = 0.f, a1 = 0.f, a2 = 0.f, a3 = 0.f;
    float b0 = 0.f, b1 = 0.f, b2 = 0.f, b3 = 0.f;
#pragma unroll
    for (int i = 0; i < 32; i++) {
        float x = sE[grp][i];
        const float4 wa = *(const float4*)&sWA[i * 32 + c4];
        const float4 wb = *(const float4*)&sWB[i * 32 + c4];
        a0 += x * wa.x; a1 += x * wa.y; a2 += x * wa.z; a3 += x * wa.w;
        b0 += x * wb.x; b1 += x * wb.y; b2 += x * wb.z; b3 += x * wb.w;
    }
    *(float4*)(A + (size_t)n * 32 + c4) = make_float4(a0, a1, a2, a3);

    unsigned int lo = ((unsigned int)__half_as_ushort(__float2half_rn(b1)) << 16)
                    | (unsigned int)__half_as_ushort(__float2half_rn(b0));
    unsigned int hi = ((unsigned int)__half_as_ushort(__float2half_rn(b3)) << 16)
                    | (unsigned int)__half_as_ushort(__float2half_rn(b2));
    *(uint2*)(Bh + (size_t)n * 32 + c4) = make_uint2(lo, hi);
}

// ---------------- kernel 4: per-bucket LDS-atomic segment max (2-way unroll) -----------
__global__ __launch_bounds__(512) void k_fine(
    const int* __restrict__ cnt, const unsigned int* __restrict__ eidx,
    const unsigned long long* __restrict__ ovf, const int* __restrict__ ovfn,
    const __half* __restrict__ Bh,
    float* __restrict__ A,             // in: A, out: agg (in place)
    const float* __restrict__ b_msg,
    float* __restrict__ pc2s, float* __restrict__ pc2q)  // [NBUCK][32] partials
{
    __shared__ unsigned int smax[128 * 33];
    __shared__ float sb[32];
    __shared__ float ps[8][32], pq[8][32];
    int tid = threadIdx.x;
    if (tid < 32) sb[tid] = b_msg[tid];
    for (int i = tid; i < 128 * 33; i += 512) smax[i] = 0u;
    __syncthreads();

    int b = blockIdx.x;
    int ne = cnt[b]; if (ne > CAPB) ne = CAPB;
    const unsigned int* eb = eidx + (size_t)b * CAPB;
    int slot = tid >> 3, sub = tid & 7;

    // 2-way unrolled gather loop: two independent eidx->Bh chains in flight
    for (int k = slot; k < ne; k += 128) {
        unsigned int p0 = eb[k];
        int k1 = k + 64;
        bool have1 = (k1 < ne);
        unsigned int p1 = have1 ? eb[k1] : 0u;

        int dl0 = (int)(p0 >> 17);
        int s0i = (int)(p0 & 0x1FFFFu);
        uint2 hv0 = *(const uint2*)(Bh + (size_t)s0i * 32 + sub * 4);
        int dl1 = 0; uint2 hv1 = make_uint2(0u, 0u);
        if (have1) {
            dl1 = (int)(p1 >> 17);
            int s1i = (int)(p1 & 0x1FFFFu);
            hv1 = *(const uint2*)(Bh + (size_t)s1i * 32 + sub * 4);
        }

        {
            float x0 = __half2float(__ushort_as_half((unsigned short)(hv0.x & 0xFFFFu)));
            float x1 = __half2float(__ushort_as_half((unsigned short)(hv0.x >> 16)));
            float x2 = __half2float(__ushort_as_half((unsigned short)(hv0.y & 0xFFFFu)));
            float x3 = __half2float(__ushort_as_half((unsigned short)(hv0.y >> 16)));
            unsigned int* row = &smax[dl0 * 33 + sub * 4];
            atomicMax(row + 0, encf(x0));
            atomicMax(row + 1, encf(x1));
            atomicMax(row + 2, encf(x2));
            atomicMax(row + 3, encf(x3));
        }
        if (have1) {
            float x0 = __half2float(__ushort_as_half((unsigned short)(hv1.x & 0xFFFFu)));
            float x1 = __half2float(__ushort_as_half((unsigned short)(hv1.x >> 16)));
            float x2 = __half2float(__ushort_as_half((unsigned short)(hv1.y & 0xFFFFu)));
            float x3 = __half2float(__ushort_as_half((unsigned short)(hv1.y >> 16)));
            unsigned int* row = &smax[dl1 * 33 + sub * 4];
            atomicMax(row + 0, encf(x0));
            atomicMax(row + 1, encf(x1));
            atomicMax(row + 2, encf(x2));
            atomicMax(row + 3, encf(x3));
        }
    }
    int on = *ovfn;
    for (int k = slot; k < on; k += 64) {           // normally on == 0
        unsigned long long oe = ovf[k];
        if ((int)(oe >> 32) == b) {
            unsigned int p = (unsigned int)oe;
            int dl = (int)(p >> 17);
            int s  = (int)(p & 0x1FFFFu);
            uint2 hv = *(const uint2*)(Bh + (size_t)s * 32 + sub * 4);
            float x0 = __half2float(__ushort_as_half((unsigned short)(hv.x & 0xFFFFu)));
            float x1 = __half2float(__ushort_as_half((unsigned short)(hv.x >> 16)));
            float x2 = __half2float(__ushort_as_half((unsigned short)(hv.y & 0xFFFFu)));
            float x3 = __half2float(__ushort_as_half((unsigned short)(hv.y >> 16)));
            unsigned int* row = &smax[dl * 33 + sub * 4];
            atomicMax(row + 0, encf(x0));
            atomicMax(row + 1, encf(x1));
            atomicMax(row + 2, encf(x2));
            atomicMax(row + 3, encf(x3));
        }
    }
    __syncthreads();

    float s0 = 0.f, s1 = 0.f, s2 = 0.f, s3 = 0.f;
    float q0 = 0.f, q1 = 0.f, q2 = 0.f, q3 = 0.f;
#pragma unroll
    for (int i = 0; i < 2; i++) {
        int node = slot + i * 64;
        int n = b * 128 + node;
        if (n < N_NODES) {
            unsigned int k0 = smax[node * 33 + sub * 4 + 0];
            unsigned int k1 = smax[node * 33 + sub * 4 + 1];
            unsigned int k2 = smax[node * 33 + sub * 4 + 2];
            unsigned int k3 = smax[node * 33 + sub * 4 + 3];
            float4* arow = (float4*)(A + (size_t)n * 32 + sub * 4);
            float4 a = *arow;
            float4 agg;
            agg.x = k0 ? (decf(k0) + a.x + sb[sub * 4 + 0]) : 0.f;
            agg.y = k1 ? (decf(k1) + a.y + sb[sub * 4 + 1]) : 0.f;
            agg.z = k2 ? (decf(k2) + a.z + sb[sub * 4 + 2]) : 0.f;
            agg.w = k3 ? (decf(k3) + a.w + sb[sub * 4 + 3]) : 0.f;
            *arow = agg;
            s0 += agg.x; s1 += agg.y; s2 += agg.z; s3 += agg.w;
            q0 += agg.x * agg.x; q1 += agg.y * agg.y;
            q2 += agg.z * agg.z; q3 += agg.w * agg.w;
        }
    }
#pragma unroll
    for (int o = 8; o < 64; o <<= 1) {
        s0 += __shfl_xor(s0, o, 64); s1 += __shfl_xor(s1, o, 64);
        s2 += __shfl_xor(s2, o, 64); s3 += __shfl_xor(s3, o, 64);
        q0 += __shfl_xor(q0, o, 64); q1 += __shfl_xor(q1, o, 64);
        q2 += __shfl_xor(q2, o, 64); q3 += __shfl_xor(q3, o, 64);
    }
    int lane = tid & 63, wid = tid >> 6;
    if (lane < 8) {
        ps[wid][lane * 4 + 0] = s0; ps[wid][lane * 4 + 1] = s1;
        ps[wid][lane * 4 + 2] = s2; ps[wid][lane * 4 + 3] = s3;
        pq[wid][lane * 4 + 0] = q0; pq[wid][lane * 4 + 1] = q1;
        pq[wid][lane * 4 + 2] = q2; pq[wid][lane * 4 + 3] = q3;
    }
    __syncthreads();
    if (tid < 32) {
        float fs = 0.f, fq = 0.f;
#pragma unroll
        for (int w = 0; w < 8; w++) { fs += ps[w][tid]; fq += pq[w][tid]; }
        pc2s[(size_t)b * 32 + tid] = fs;    // non-atomic partial write
        pc2q[(size_t)b * 32 + tid] = fq;
    }
}

// ---------------- kernel 4b: reduce BN2 partials (1 block) ----------------
__global__ __launch_bounds__(1024) void k_red2(
    const float* __restrict__ pc2s, const float* __restrict__ pc2q,
    float* __restrict__ sum2, float* __restrict__ sumsq2)
{
    __shared__ float rs[32][33], rq[32][33];
    int tid = threadIdx.x;
    int c = tid & 31, r0 = tid >> 5;   // 32 row-strides
    float s = 0.f, q = 0.f;
    for (int r = r0; r < NBUCK; r += 32) {
        s += pc2s[(size_t)r * 32 + c];
        q += pc2q[(size_t)r * 32 + c];
    }
    rs[r0][c] = s; rq[r0][c] = q;
    __syncthreads();
    if (tid < 32) {
        float fs = 0.f, fq = 0.f;
#pragma unroll
        for (int r = 0; r < 32; r++) { fs += rs[r][tid]; fq += rq[r][tid]; }
        sum2[tid] = fs;
        sumsq2[tid] = fq;
    }
}

// ---------------- kernel 5: BN1-affine + BN2-affine + output head (8 lanes/node) -------
__global__ __launch_bounds__(256) void k_out(
    const float* __restrict__ emb,
    const float* __restrict__ agg,
    const float* __restrict__ g1, const float* __restrict__ be1,
    const float* __restrict__ sum1, const float* __restrict__ sumsq1,
    const float* __restrict__ g2, const float* __restrict__ be2,
    const float* __restrict__ sum2, const float* __restrict__ sumsq2,
    const float* __restrict__ W_o1, const float* __restrict__ b_o1,
    const float* __restrict__ W_o2, const float* __restrict__ b_o2,
    float* __restrict__ out)
{
    __shared__ __align__(16) float sW1[32 * 16];
    __shared__ float sb1o[16], sW2[16];
    __shared__ float sa1[32], sb1c[32], sa2[32], sb2c[32];
    __shared__ float sH[32][33];
    __shared__ float sb2s;
    int tid = threadIdx.x;
    for (int t = tid; t < 512; t += 256) sW1[t] = W_o1[t];
    if (tid < 16) { sW2[tid] = W_o2[tid]; sb1o[tid] = b_o1[tid]; }
    if (tid < 32) {
        float m1 = sum1[tid] / (float)N_NODES;
        float v1 = sumsq1[tid] / (float)N_NODES - m1 * m1;
        float i1 = 1.0f / sqrtf(v1 + BN_EPS);
        float a1 = g1[tid] * i1;
        sa1[tid] = a1;
        sb1c[tid] = be1[tid] - a1 * m1;
        float m2 = sum2[tid] / (float)N_NODES;
        float v2 = sumsq2[tid] / (float)N_NODES - m2 * m2;
        float i2 = 1.0f / sqrtf(v2 + BN_EPS);
        float a2 = g2[tid] * i2;
        sa2[tid] = a2;
        sb2c[tid] = be2[tid] - a2 * m2;
    }
    if (tid == 0) sb2s = b_o2[0];
    __syncthreads();

    int grp = tid >> 3, sub = tid & 7;
    int n = blockIdx.x * 32 + grp;
    int c4 = sub * 4;

    float4 ev = *(const float4*)(emb + (size_t)n * 32 + c4);
    float4 av = *(const float4*)(agg + (size_t)n * 32 + c4);
    sH[grp][c4 + 0] = sa1[c4 + 0] * ev.x + sb1c[c4 + 0] + sa2[c4 + 0] * av.x + sb2c[c4 + 0];
    sH[grp][c4 + 1] = sa1[c4 + 1] * ev.y + sb1c[c4 + 1] + sa2[c4 + 1] * av.y + sb2c[c4 + 1];
    sH[grp][c4 + 2] = sa1[c4 + 2] * ev.z + sb1c[c4 + 2] + sa2[c4 + 2] * av.z + sb2c[c4 + 2];
    sH[grp][c4 + 3] = sa1[c4 + 3] * ev.w + sb1c[c4 + 3] + sa2[c4 + 3] * av.w + sb2c[c4 + 3];
    __syncthreads();   // LDS exchange barrier (R11 lesson)

    int c0 = sub * 2;
    float o0 = sb1o[c0], o1v = sb1o[c0 + 1];
#pragma unroll
    for (int i = 0; i < 32; i++) {
        float x = sH[grp][i];
        o0  += x * sW1[i * 16 + c0];
        o1v += x * sW1[i * 16 + c0 + 1];
    }
    float psum = eluf(o0) * sW2[c0] + eluf(o1v) * sW2[c0 + 1];
    psum += __shfl_xor(psum, 1, 64);
    psum += __shfl_xor(psum, 2, 64);
    psum += __shfl_xor(psum, 4, 64);
    if (sub == 0) out[n] = psum + sb2s;
}

extern "C" void kernel_launch(void* const* d_in, const int* in_sizes, int n_in,
                              void* d_out, int out_size, void* d_ws, size_t ws_size,
                              hipStream_t stream)
{
    const float* x_cont     = (const float*)d_in[0];
    const int*   x_cat      = (const int*)d_in[1];
    const int*   edge_index = (const int*)d_in[2];
    const float* datanorm   = (const float*)d_in[4];
    const float* W_cont     = (const float*)d_in[5];
    const float* b_cont     = (const float*)d_in[6];
    const float* emb_charge = (const float*)d_in[7];
    const float* emb_pdg    = (const float*)d_in[8];
    const float* W_cat      = (const float*)d_in[9];
    const float* b_cat      = (const float*)d_in[10];
    const float* W_enc      = (const float*)d_in[11];
    const float* b_enc      = (const float*)d_in[12];
    const float* g_all      = (const float*)d_in[13];
    const float* be_all     = (const float*)d_in[14];
    const float* W_msg      = (const float*)d_in[15];
    const float* b_msg      = (const float*)d_in[16];
    const float* g_conv     = (const float*)d_in[17];
    const float* be_conv    = (const float*)d_in[18];
    const float* W_o1       = (const float*)d_in[19];
    const float* b_o1       = (const float*)d_in[20];
    const float* W_o2       = (const float*)d_in[21];
    const float* b_o2       = (const float*)d_in[22];

    const size_t NH = (size_t)N_NODES * 32;
    float* buf_emb = (float*)d_ws;                          // NH floats (raw)
    float* buf_A   = buf_emb + NH;                          // NH floats
    __half* buf_Bh = (__half*)(buf_A + NH);                 // NH halves
    unsigned long long* ovf = (unsigned long long*)(buf_Bh + NH);  // OVF_MAX
    // zeroed region: stats(256f) | cnt(NBUCK) | ovfn(1)  -> single memset
    float* stats   = (float*)(ovf + OVF_MAX);               // 256 floats
    int*   cnt     = (int*)(stats + 256);                   // NBUCK
    int*   ovfn    = cnt + NBUCK;                           // 1
    float* pc2s    = (float*)(ovfn + 1);                    // NBUCK*32
    float* pc2q    = pc2s + (size_t)NBUCK * 32;             // NBUCK*32
    unsigned int* eidx = (unsigned int*)(pc2q + (size_t)NBUCK * 32);  // NBUCK*CAPB

    float* sum1 = stats,       *sumsq1 = stats + 32;
    float* sum2 = stats + 128, *sumsq2 = stats + 160;

    hipMemsetAsync(stats, 0, (256 + NBUCK + 1) * sizeof(int), stream);

    const int* src = edge_index;
    const int* dst = edge_index + N_EDGES;

    k_encode<<<NB32, 256, 0, stream>>>(x_cont, x_cat, datanorm, W_cont, b_cont,
                                       emb_charge, emb_pdg, W_cat, b_cat, W_enc, b_enc,
                                       buf_emb);
    k_statbin<<<BIN_BLKS + STAT_BLKS, 1024, 0, stream>>>(src, dst, cnt, eidx, ovf, ovfn,
                                                         buf_emb, sum1, sumsq1);
    k_normAB<<<NB32, 256, 0, stream>>>(buf_emb, W_msg, g_all, be_all, sum1, sumsq1, buf_A, buf_Bh);
    k_fine<<<NBUCK, 512, 0, stream>>>(cnt, eidx, ovf, ovfn, buf_Bh, buf_A, b_msg, pc2s, pc2q);
    k_red2<<<1, 1024, 0, stream>>>(pc2s, pc2q, sum2, sumsq2);
    k_out<<<NB32, 256, 0, stream>>>(buf_emb, buf_A, g_all, be_all, sum1, sumsq1,
                                    g_conv, be_conv, sum2, sumsq2,
                                    W_o1, b_o1, W_o2, b_o2, (float*)d_out);
}